// Round 11
// baseline (235.475 us; speedup 1.0000x reference)
//
#include <hip/hip_runtime.h>
#include <cstddef>

#define N_ENT   2000
#define GAT_EMB 64
#define HIDDEN  256
#define BATCH   8
#define ALPHA   0.2f
#define NROWS   (BATCH * N_ENT)          // 16000
#define N4TOT   (NROWS * N_ENT / 4)      // 8,000,000 int4s in adj

typedef _Float16 half4 __attribute__((ext_vector_type(4)));

// ws byte layout:
//   [0,      8192)    s2f  float[2048]      (pad zeroed by k_prep)
//   [8192,  12288)    hx   _Float16[2048]   (pad zeroed)
//   [12288, 16384)    hy   _Float16[2048]
//   [16384, 20480)    hz   _Float16[2048]
//   [20480, 28672)    s1f  float[2048]
//   [28672, 124672)   x16  _Float16[6000][8]
//   [124672, 32124672) bmask uchar[16000][2000]  (1 byte per adj element)
#define WS_HX_OFF      8192
#define WS_HY_OFF      12288
#define WS_HZ_OFF      16384
#define WS_S1_OFF      20480
#define WS_X_OFF       28672
#define WS_MASK_OFF    124672
#define WS_TIER2_BYTES 32124672

__global__ __launch_bounds__(256) void k_init(const float* __restrict__ fc1_b,
                                              float* __restrict__ out) {
    int idx = blockIdx.x * 256 + threadIdx.x;
    out[idx] = fc1_b[idx & (HIDDEN - 1)];
}

// Table build; 2048 threads cover the pad (zeroed).
__global__ __launch_bounds__(256) void k_prep(const float* __restrict__ emb,
                                              const float* __restrict__ W,
                                              const float* __restrict__ a,
                                              float* __restrict__ ws) {
    __shared__ float sW[GAT_EMB * 3];
    __shared__ float sa[6];
    int t = threadIdx.x;
    if (t < GAT_EMB * 3) sW[t] = W[t];
    if (t < 6)           sa[t] = a[t];
    __syncthreads();
    int i = blockIdx.x * 256 + t;
    if (i >= 2048) return;
    if (i >= N_ENT) {
        ws[i] = 0.f;
        ((_Float16*)((char*)ws + WS_HX_OFF))[i] = (_Float16)0;
        ((_Float16*)((char*)ws + WS_HY_OFF))[i] = (_Float16)0;
        ((_Float16*)((char*)ws + WS_HZ_OFF))[i] = (_Float16)0;
        ws[WS_S1_OFF / 4 + i] = 0.f;
        return;
    }
    const float4* er = (const float4*)(emb + (size_t)i * GAT_EMB);
    float h0 = 0.f, h1 = 0.f, h2 = 0.f;
#pragma unroll
    for (int k4 = 0; k4 < GAT_EMB / 4; ++k4) {
        float4 e4 = er[k4];
        int k = 4 * k4;
        h0 += e4.x * sW[(k + 0) * 3 + 0]; h1 += e4.x * sW[(k + 0) * 3 + 1]; h2 += e4.x * sW[(k + 0) * 3 + 2];
        h0 += e4.y * sW[(k + 1) * 3 + 0]; h1 += e4.y * sW[(k + 1) * 3 + 1]; h2 += e4.y * sW[(k + 1) * 3 + 2];
        h0 += e4.z * sW[(k + 2) * 3 + 0]; h1 += e4.z * sW[(k + 2) * 3 + 1]; h2 += e4.z * sW[(k + 2) * 3 + 2];
        h0 += e4.w * sW[(k + 3) * 3 + 0]; h1 += e4.w * sW[(k + 3) * 3 + 1]; h2 += e4.w * sW[(k + 3) * 3 + 2];
    }
    ws[i] = h0 * sa[3] + h1 * sa[4] + h2 * sa[5];                       // s2
    ((_Float16*)((char*)ws + WS_HX_OFF))[i] = (_Float16)h0;
    ((_Float16*)((char*)ws + WS_HY_OFF))[i] = (_Float16)h1;
    ((_Float16*)((char*)ws + WS_HZ_OFF))[i] = (_Float16)h2;
    ws[WS_S1_OFF / 4 + i] = h0 * sa[0] + h1 * sa[1] + h2 * sa[2];       // s1
}

// FLAT grid-stride byte-pack: identical access shape to the 6.9 TB/s fill.
// Thread reads int4 at flat index i, writes uchar4 at i. Dense sweeping front
// (resident waves cover one contiguous ~8 MB window), no cross-lane ops.
__global__ __launch_bounds__(256) void k_pack(const int4* __restrict__ adj4,
                                              uchar4* __restrict__ m4) {
    int idx    = blockIdx.x * 256 + threadIdx.x;
    int stride = gridDim.x * 256;
    for (int i = idx; i < N4TOT; i += stride) {
        int4 v = adj4[i];
        m4[i] = make_uchar4(v.x > 0 ? 1 : 0, v.y > 0 ? 1 : 0,
                            v.z > 0 ? 1 : 0, v.w > 0 ? 1 : 0);
    }
}

// GAT on byte-masks (32 MB, L3-resident): 1000 blocks x 16 rows (one batch b).
// Wave w: rows +4w..+3; per chunk per row one 256 B uchar4 load. Numerics as r9.
__global__ __launch_bounds__(256, 4) void k_gat(const unsigned char* __restrict__ bmask,
                                                const float* __restrict__ wsf,
                                                float* __restrict__ wsx) {
    __shared__ __align__(16) unsigned char smem[20480];
    float*    s2s = (float*)smem;
    _Float16* hxs = (_Float16*)(smem + 8192);
    _Float16* hys = (_Float16*)(smem + 12288);
    _Float16* hzs = (_Float16*)(smem + 16384);
    __shared__ float s1sh[16];

    int t = threadIdx.x;
    int R0 = blockIdx.x * 16;
    int b  = R0 / N_ENT;
    int i_base = R0 - b * N_ENT;

    {
        const uint4* src = (const uint4*)wsf;
        uint4* dst = (uint4*)smem;
#pragma unroll
        for (int rep = 0; rep < 5; ++rep) dst[rep * 256 + t] = src[rep * 256 + t];  // 20480 B
        if (t < 16) s1sh[t] = wsf[WS_S1_OFF / 4 + i_base + t];
    }
    __syncthreads();

    int lane = t & 63;
    int w    = t >> 6;
    float s1r[4];
    const unsigned char* __restrict__ mrow[4];
#pragma unroll
    for (int r = 0; r < 4; ++r) {
        s1r[r] = s1sh[4 * w + r];
        mrow[r] = bmask + (size_t)(R0 + 4 * w + r) * N_ENT;
    }

    float acc[4][4];
#pragma unroll
    for (int r = 0; r < 4; ++r) { acc[r][0] = 0.f; acc[r][1] = 0.f; acc[r][2] = 0.f; acc[r][3] = 0.f; }

    int l4 = lane << 2;
#pragma unroll
    for (int c = 0; c < 8; ++c) {
        int j0 = c * 256 + l4;                  // <= 2044; LDS pad zeroed
        bool valid = (j0 < N_ENT);
        int jc = valid ? j0 : 0;
        float vw = valid ? 1.0f : 0.0f;
        uchar4 mb[4];
#pragma unroll
        for (int r = 0; r < 4; ++r) mb[r] = *(const uchar4*)(mrow[r] + jc);
        float4 s2v = *(const float4*)&s2s[j0];
        half4  hxv = *(const half4*)&hxs[j0];
        half4  hyv = *(const half4*)&hys[j0];
        half4  hzv = *(const half4*)&hzs[j0];
        float hx[4], hy[4], hz[4];
#pragma unroll
        for (int q = 0; q < 4; ++q) { hx[q] = (float)hxv[q]; hy[q] = (float)hyv[q]; hz[q] = (float)hzv[q]; }
#pragma unroll
        for (int r = 0; r < 4; ++r) {
            const unsigned char* mc = (const unsigned char*)&mb[r];
#pragma unroll
            for (int q = 0; q < 4; ++q) {
                float e  = s1r[r] + ((const float*)&s2v)[q];
                float ev = __expf(fmaxf(e, 0.f) + ALPHA * fminf(e, 0.f));
                float contrib = ((mc[q] > 0) ? ev : 1.0f) * vw;   // expf(9e-15)==1.0f exactly
                acc[r][0] += contrib;
                acc[r][1] += contrib * hx[q];
                acc[r][2] += contrib * hy[q];
                acc[r][3] += contrib * hz[q];
            }
        }
    }

#pragma unroll
    for (int off = 32; off > 0; off >>= 1)
#pragma unroll
        for (int r = 0; r < 4; ++r) {
            acc[r][0] += __shfl_xor(acc[r][0], off, 64);
            acc[r][1] += __shfl_xor(acc[r][1], off, 64);
            acc[r][2] += __shfl_xor(acc[r][2], off, 64);
            acc[r][3] += __shfl_xor(acc[r][3], off, 64);
        }

    if (lane == 0) {
        _Float16* x16 = (_Float16*)((char*)wsx + WS_X_OFF);
#pragma unroll
        for (int r = 0; r < 4; ++r) {
            float inv = 1.f / acc[r][0];
            float p0 = acc[r][1] * inv, p1 = acc[r][2] * inv, p2 = acc[r][3] * inv;
            p0 = (p0 > 0.f) ? p0 : expm1f(p0);   // ELU
            p1 = (p1 > 0.f) ? p1 : expm1f(p1);
            p2 = (p2 > 0.f) ? p2 : expm1f(p2);
            int i = i_base + 4 * w + r;
            x16[(size_t)(3 * i + 0) * 8 + b] = (_Float16)p0;
            x16[(size_t)(3 * i + 1) * 8 + b] = (_Float16)p1;
            x16[(size_t)(3 * i + 2) * 8 + b] = (_Float16)p2;
        }
    }
}

// out[b,k] = fc1_b[k] + sum_m x16[m][b] * fc1_w[k][m]; 256 blocks (one per k).
__global__ __launch_bounds__(256) void k_fc(const _Float16* __restrict__ x16,
                                            const float* __restrict__ fc1_w,
                                            const float* __restrict__ fc1_b,
                                            float* __restrict__ out) {
    __shared__ float red[4][8];
    int t = threadIdx.x, lane = t & 63, w = t >> 6;
    int k = blockIdx.x;
    const float* __restrict__ wr = fc1_w + (size_t)k * (N_ENT * 3);
    float acc[BATCH];
#pragma unroll
    for (int b = 0; b < BATCH; ++b) acc[b] = 0.f;
#pragma unroll
    for (int it = 0; it < 6; ++it) {
        int m0 = 4 * t + 1024 * it;
        if (m0 + 3 < N_ENT * 3) {
            float4 wv4 = *(const float4*)(wr + m0);
#pragma unroll
            for (int q = 0; q < 4; ++q) {
                half4 xa = *(const half4*)(x16 + (size_t)(m0 + q) * 8);
                half4 xb = *(const half4*)(x16 + (size_t)(m0 + q) * 8 + 4);
                float wv = ((const float*)&wv4)[q];
                acc[0] += wv * (float)xa[0]; acc[1] += wv * (float)xa[1];
                acc[2] += wv * (float)xa[2]; acc[3] += wv * (float)xa[3];
                acc[4] += wv * (float)xb[0]; acc[5] += wv * (float)xb[1];
                acc[6] += wv * (float)xb[2]; acc[7] += wv * (float)xb[3];
            }
        }
    }
#pragma unroll
    for (int off = 32; off > 0; off >>= 1)
#pragma unroll
        for (int b = 0; b < BATCH; ++b) acc[b] += __shfl_xor(acc[b], off, 64);
    if (lane == 0)
#pragma unroll
        for (int b = 0; b < BATCH; ++b) red[w][b] = acc[b];
    __syncthreads();
    if (t < 8)
        out[t * HIDDEN + k] = red[0][t] + red[1][t] + red[2][t] + red[3][t] + fc1_b[k];
}

// ---- Fallback (small/no workspace): self-contained, atomic FC ----
__global__ __launch_bounds__(256, 5) void k_main_fb(const float* __restrict__ emb,
                                                    const float* __restrict__ W,
                                                    const float* __restrict__ a,
                                                    const float* __restrict__ fc1_w,
                                                    const int*   __restrict__ adj,
                                                    float* __restrict__ out) {
    __shared__ __align__(16) unsigned char smem[20480];
    float*    s2s = (float*)smem;
    _Float16* hxs = (_Float16*)(smem + 8192);
    _Float16* hys = (_Float16*)(smem + 12288);
    _Float16* hzs = (_Float16*)(smem + 16384);
    __shared__ float sW[GAT_EMB * 3];
    __shared__ float sa[6];
    __shared__ float s1sh[16];
    __shared__ float xblk[48];

    int t = threadIdx.x;
    int R0 = blockIdx.x * 16;
    int b  = R0 / N_ENT;
    int i_base = R0 - b * N_ENT;

    if (t < GAT_EMB * 3) sW[t] = W[t];
    if (t < 6)           sa[t] = a[t];
    __syncthreads();
    for (int j = t; j < N_ENT; j += 256) {
        const float4* er = (const float4*)(emb + (size_t)j * GAT_EMB);
        float h0 = 0.f, h1 = 0.f, h2 = 0.f;
#pragma unroll
        for (int k4 = 0; k4 < GAT_EMB / 4; ++k4) {
            float4 e4 = er[k4];
            int k = 4 * k4;
            h0 += e4.x * sW[(k + 0) * 3 + 0]; h1 += e4.x * sW[(k + 0) * 3 + 1]; h2 += e4.x * sW[(k + 0) * 3 + 2];
            h0 += e4.y * sW[(k + 1) * 3 + 0]; h1 += e4.y * sW[(k + 1) * 3 + 1]; h2 += e4.y * sW[(k + 1) * 3 + 2];
            h0 += e4.z * sW[(k + 2) * 3 + 0]; h1 += e4.z * sW[(k + 2) * 3 + 1]; h2 += e4.z * sW[(k + 2) * 3 + 2];
            h0 += e4.w * sW[(k + 3) * 3 + 0]; h1 += e4.w * sW[(k + 3) * 3 + 1]; h2 += e4.w * sW[(k + 3) * 3 + 2];
        }
        s2s[j] = h0 * sa[3] + h1 * sa[4] + h2 * sa[5];
        hxs[j] = (_Float16)h0; hys[j] = (_Float16)h1; hzs[j] = (_Float16)h2;
        if (j >= i_base && j < i_base + 16)
            s1sh[j - i_base] = h0 * sa[0] + h1 * sa[1] + h2 * sa[2];
    }
    if (t < 2048 - N_ENT) {
        int j = N_ENT + t;
        s2s[j] = 0.f; hxs[j] = (_Float16)0; hys[j] = (_Float16)0; hzs[j] = (_Float16)0;
    }
    __syncthreads();

    int lane = t & 63;
    int w    = t >> 6;
    float s1r[4];
    const int* __restrict__ rowp[4];
#pragma unroll
    for (int r = 0; r < 4; ++r) {
        s1r[r] = s1sh[4 * w + r];
        rowp[r] = adj + ((size_t)b * N_ENT + (i_base + 4 * w + r)) * N_ENT;
    }
    float acc[4][4];
#pragma unroll
    for (int r = 0; r < 4; ++r) { acc[r][0] = 0.f; acc[r][1] = 0.f; acc[r][2] = 0.f; acc[r][3] = 0.f; }
    int l4 = lane << 2;
#pragma unroll
    for (int c = 0; c < 8; ++c) {
        int j0 = c * 256 + l4;
        bool valid = (j0 < N_ENT);
        int jc = valid ? j0 : 0;
        int4 m0 = *(const int4*)(rowp[0] + jc);
        int4 m1 = *(const int4*)(rowp[1] + jc);
        int4 m2 = *(const int4*)(rowp[2] + jc);
        int4 m3 = *(const int4*)(rowp[3] + jc);
        float4 s2v = *(const float4*)&s2s[j0];
        half4  hxv = *(const half4*)&hxs[j0];
        half4  hyv = *(const half4*)&hys[j0];
        half4  hzv = *(const half4*)&hzs[j0];
        float hx[4], hy[4], hz[4];
#pragma unroll
        for (int q = 0; q < 4; ++q) { hx[q] = (float)hxv[q]; hy[q] = (float)hyv[q]; hz[q] = (float)hzv[q]; }
        const int* mm[4] = { (const int*)&m0, (const int*)&m1, (const int*)&m2, (const int*)&m3 };
        float vw = valid ? 1.0f : 0.0f;
#pragma unroll
        for (int r = 0; r < 4; ++r)
#pragma unroll
            for (int q = 0; q < 4; ++q) {
                float e  = s1r[r] + ((const float*)&s2v)[q];
                float ev = __expf(fmaxf(e, 0.f) + ALPHA * fminf(e, 0.f));
                float contrib = ((mm[r][q] > 0) ? ev : 1.0f) * vw;
                acc[r][0] += contrib; acc[r][1] += contrib * hx[q];
                acc[r][2] += contrib * hy[q]; acc[r][3] += contrib * hz[q];
            }
    }
#pragma unroll
    for (int off = 32; off > 0; off >>= 1)
#pragma unroll
        for (int r = 0; r < 4; ++r) {
            acc[r][0] += __shfl_xor(acc[r][0], off, 64);
            acc[r][1] += __shfl_xor(acc[r][1], off, 64);
            acc[r][2] += __shfl_xor(acc[r][2], off, 64);
            acc[r][3] += __shfl_xor(acc[r][3], off, 64);
        }
    if (lane == 0)
#pragma unroll
        for (int r = 0; r < 4; ++r) {
            float inv = 1.f / acc[r][0];
            float p0 = acc[r][1] * inv, p1 = acc[r][2] * inv, p2 = acc[r][3] * inv;
            int cc = 3 * (4 * w + r);
            xblk[cc + 0] = (p0 > 0.f) ? p0 : expm1f(p0);
            xblk[cc + 1] = (p1 > 0.f) ? p1 : expm1f(p1);
            xblk[cc + 2] = (p2 > 0.f) ? p2 : expm1f(p2);
        }
    __syncthreads();
    int k = (t + R0) & 255;
    const float* wr = fc1_w + (size_t)k * (N_ENT * 3) + 3 * i_base;
    float d = 0.f;
#pragma unroll
    for (int c4 = 0; c4 < 12; ++c4) {
        float4 wv = *(const float4*)(wr + 4 * c4);
        d += xblk[4 * c4 + 0] * wv.x + xblk[4 * c4 + 1] * wv.y
           + xblk[4 * c4 + 2] * wv.z + xblk[4 * c4 + 3] * wv.w;
    }
    atomicAdd(&out[b * HIDDEN + k], d);
}

extern "C" void kernel_launch(void* const* d_in, const int* in_sizes, int n_in,
                              void* d_out, int out_size, void* d_ws, size_t ws_size,
                              hipStream_t stream) {
    const float* emb   = (const float*)d_in[0];
    const float* W     = (const float*)d_in[1];
    const float* a     = (const float*)d_in[2];
    const float* fc1_w = (const float*)d_in[3];
    const float* fc1_b = (const float*)d_in[4];
    const int*   adj   = (const int*)d_in[5];
    float* out = (float*)d_out;
    float* ws  = (float*)d_ws;
    (void)in_sizes; (void)n_in; (void)out_size;

    if (ws_size >= (size_t)WS_TIER2_BYTES) {
        k_prep<<<8, 256, 0, stream>>>(emb, W, a, ws);
        k_pack<<<2048, 256, 0, stream>>>((const int4*)adj,
                                         (uchar4*)((char*)d_ws + WS_MASK_OFF));
        k_gat<<<1000, 256, 0, stream>>>((const unsigned char*)((char*)d_ws + WS_MASK_OFF),
                                        ws, ws);
        k_fc<<<HIDDEN, 256, 0, stream>>>((const _Float16*)((char*)d_ws + WS_X_OFF),
                                         fc1_w, fc1_b, out);
    } else {
        k_init<<<8, 256, 0, stream>>>(fc1_b, out);
        k_main_fb<<<1000, 256, 0, stream>>>(emb, W, a, fc1_w, adj, out);
    }
}

// Round 12
// 202.529 us; speedup vs baseline: 1.1627x; 1.1627x over previous
//
#include <hip/hip_runtime.h>
#include <cstddef>

#define N_ENT   2000
#define GAT_EMB 64
#define HIDDEN  256
#define BATCH   8
#define ALPHA   0.2f

typedef _Float16 half4 __attribute__((ext_vector_type(4)));
typedef int iv4 __attribute__((ext_vector_type(4)));

// Non-temporal 16B load of adj (streaming, read-once): NT bit -> no/evict-first
// cache allocation, avoiding dirty-victim writebacks from the harness's 512 MB
// 0xAA poison fill that precedes every launch.
__device__ __forceinline__ iv4 nt_load4(const int* p) {
    return __builtin_nontemporal_load((const iv4*)p);
}

// ws byte layout:
//   [0,      8192)   s2f  float[2048]      (pad zeroed by k_prep)
//   [8192,  12288)   hx   _Float16[2048]   (pad zeroed)
//   [12288, 16384)   hy   _Float16[2048]
//   [16384, 20480)   hz   _Float16[2048]
//   [20480, 28672)   s1f  float[2048]
//   [28672, 124672)  x16  _Float16[6000][8]
#define WS_HX_OFF      8192
#define WS_HY_OFF      12288
#define WS_HZ_OFF      16384
#define WS_S1_OFF      20480
#define WS_X_OFF       28672
#define WS_TABLE_BYTES 28672
#define WS_TIER2_BYTES 124672

__global__ __launch_bounds__(256) void k_init(const float* __restrict__ fc1_b,
                                              float* __restrict__ out) {
    int idx = blockIdx.x * 256 + threadIdx.x;
    out[idx] = fc1_b[idx & (HIDDEN - 1)];
}

// Table build; 2048 threads cover the pad (zeroed).
__global__ __launch_bounds__(256) void k_prep(const float* __restrict__ emb,
                                              const float* __restrict__ W,
                                              const float* __restrict__ a,
                                              float* __restrict__ ws) {
    __shared__ float sW[GAT_EMB * 3];
    __shared__ float sa[6];
    int t = threadIdx.x;
    if (t < GAT_EMB * 3) sW[t] = W[t];
    if (t < 6)           sa[t] = a[t];
    __syncthreads();
    int i = blockIdx.x * 256 + t;
    if (i >= 2048) return;
    if (i >= N_ENT) {
        ws[i] = 0.f;
        ((_Float16*)((char*)ws + WS_HX_OFF))[i] = (_Float16)0;
        ((_Float16*)((char*)ws + WS_HY_OFF))[i] = (_Float16)0;
        ((_Float16*)((char*)ws + WS_HZ_OFF))[i] = (_Float16)0;
        ws[WS_S1_OFF / 4 + i] = 0.f;
        return;
    }
    const float4* er = (const float4*)(emb + (size_t)i * GAT_EMB);
    float h0 = 0.f, h1 = 0.f, h2 = 0.f;
#pragma unroll
    for (int k4 = 0; k4 < GAT_EMB / 4; ++k4) {
        float4 e4 = er[k4];
        int k = 4 * k4;
        h0 += e4.x * sW[(k + 0) * 3 + 0]; h1 += e4.x * sW[(k + 0) * 3 + 1]; h2 += e4.x * sW[(k + 0) * 3 + 2];
        h0 += e4.y * sW[(k + 1) * 3 + 0]; h1 += e4.y * sW[(k + 1) * 3 + 1]; h2 += e4.y * sW[(k + 1) * 3 + 2];
        h0 += e4.z * sW[(k + 2) * 3 + 0]; h1 += e4.z * sW[(k + 2) * 3 + 1]; h2 += e4.z * sW[(k + 2) * 3 + 2];
        h0 += e4.w * sW[(k + 3) * 3 + 0]; h1 += e4.w * sW[(k + 3) * 3 + 1]; h2 += e4.w * sW[(k + 3) * 3 + 2];
    }
    ws[i] = h0 * sa[3] + h1 * sa[4] + h2 * sa[5];                       // s2
    ((_Float16*)((char*)ws + WS_HX_OFF))[i] = (_Float16)h0;
    ((_Float16*)((char*)ws + WS_HY_OFF))[i] = (_Float16)h1;
    ((_Float16*)((char*)ws + WS_HZ_OFF))[i] = (_Float16)h2;
    ws[WS_S1_OFF / 4 + i] = h0 * sa[0] + h1 * sa[1] + h2 * sa[2];       // s1
}

// r9 structure (best total so far), with NON-TEMPORAL adj loads.
// 1000 blocks x 16 contiguous rows (one batch b); wave w: rows i_base+4w..+3
// (4 streams 8 KB apart), 2-chunk-ahead 3-buffer register prefetch.
__global__ __launch_bounds__(256, 4) void k_main(const float* __restrict__ emb,
                                                 const float* __restrict__ W,
                                                 const float* __restrict__ a,
                                                 const float* __restrict__ fc1_w,
                                                 const int*   __restrict__ adj,
                                                 float* __restrict__ wsf,
                                                 int mode,
                                                 float* __restrict__ out) {
    __shared__ __align__(16) unsigned char smem[20480];
    float*    s2s = (float*)smem;
    _Float16* hxs = (_Float16*)(smem + 8192);
    _Float16* hys = (_Float16*)(smem + 12288);
    _Float16* hzs = (_Float16*)(smem + 16384);
    __shared__ float sW[GAT_EMB * 3];
    __shared__ float sa[6];
    __shared__ float s1sh[16];
    __shared__ float xblk[48];

    int t = threadIdx.x;
    int R0 = blockIdx.x * 16;        // global row (b*N_ENT + i); 16 | 2000 -> no straddle
    int b  = R0 / N_ENT;
    int i_base = R0 - b * N_ENT;

    if (mode != 0) {
        const uint4* src = (const uint4*)wsf;
        uint4* dst = (uint4*)smem;
#pragma unroll
        for (int rep = 0; rep < 5; ++rep) dst[rep * 256 + t] = src[rep * 256 + t];  // 20480 B
        if (t < 16) s1sh[t] = wsf[WS_S1_OFF / 4 + i_base + t];
    } else {
        if (t < GAT_EMB * 3) sW[t] = W[t];
        if (t < 6)           sa[t] = a[t];
        __syncthreads();
        for (int j = t; j < N_ENT; j += 256) {
            const float4* er = (const float4*)(emb + (size_t)j * GAT_EMB);
            float h0 = 0.f, h1 = 0.f, h2 = 0.f;
#pragma unroll
            for (int k4 = 0; k4 < GAT_EMB / 4; ++k4) {
                float4 e4 = er[k4];
                int k = 4 * k4;
                h0 += e4.x * sW[(k + 0) * 3 + 0]; h1 += e4.x * sW[(k + 0) * 3 + 1]; h2 += e4.x * sW[(k + 0) * 3 + 2];
                h0 += e4.y * sW[(k + 1) * 3 + 0]; h1 += e4.y * sW[(k + 1) * 3 + 1]; h2 += e4.y * sW[(k + 1) * 3 + 2];
                h0 += e4.z * sW[(k + 2) * 3 + 0]; h1 += e4.z * sW[(k + 2) * 3 + 1]; h2 += e4.z * sW[(k + 2) * 3 + 2];
                h0 += e4.w * sW[(k + 3) * 3 + 0]; h1 += e4.w * sW[(k + 3) * 3 + 1]; h2 += e4.w * sW[(k + 3) * 3 + 2];
            }
            s2s[j] = h0 * sa[3] + h1 * sa[4] + h2 * sa[5];
            hxs[j] = (_Float16)h0; hys[j] = (_Float16)h1; hzs[j] = (_Float16)h2;
            if (j >= i_base && j < i_base + 16)
                s1sh[j - i_base] = h0 * sa[0] + h1 * sa[1] + h2 * sa[2];
        }
        if (t < 2048 - N_ENT) {
            int j = N_ENT + t;
            s2s[j] = 0.f; hxs[j] = (_Float16)0; hys[j] = (_Float16)0; hzs[j] = (_Float16)0;
        }
    }
    __syncthreads();

    // ---- Phase 2: 4 rows/wave, 8 chunks, 2-chunk-ahead NT prefetch ----
    int lane = t & 63;
    int w    = t >> 6;
    float s1r[4];
    const int* __restrict__ rowp[4];
#pragma unroll
    for (int r = 0; r < 4; ++r) {
        s1r[r] = s1sh[4 * w + r];
        rowp[r] = adj + ((size_t)b * N_ENT + (i_base + 4 * w + r)) * N_ENT;
    }

    float acc[4][4];
#pragma unroll
    for (int r = 0; r < 4; ++r) { acc[r][0] = 0.f; acc[r][1] = 0.f; acc[r][2] = 0.f; acc[r][3] = 0.f; }

    int l4 = lane << 2;
    iv4 buf[3][4];
#pragma unroll
    for (int r = 0; r < 4; ++r) buf[0][r] = nt_load4(rowp[r] + l4);
#pragma unroll
    for (int r = 0; r < 4; ++r) buf[1][r] = nt_load4(rowp[r] + 256 + l4);

#pragma unroll
    for (int c = 0; c < 8; ++c) {
        if (c + 2 < 8) {
            int j2 = (c + 2) * 256 + l4;
            int jc2 = (j2 < N_ENT) ? j2 : 0;
#pragma unroll
            for (int r = 0; r < 4; ++r)
                buf[(c + 2) % 3][r] = nt_load4(rowp[r] + jc2);
        }
        int j0 = c * 256 + l4;                 // <= 2044; LDS pad zeroed
        bool valid = (j0 < N_ENT);
        float vw = valid ? 1.0f : 0.0f;
        float4 s2v = *(const float4*)&s2s[j0];
        half4  hxv = *(const half4*)&hxs[j0];
        half4  hyv = *(const half4*)&hys[j0];
        half4  hzv = *(const half4*)&hzs[j0];
        float hx[4], hy[4], hz[4];
#pragma unroll
        for (int q = 0; q < 4; ++q) { hx[q] = (float)hxv[q]; hy[q] = (float)hyv[q]; hz[q] = (float)hzv[q]; }
#pragma unroll
        for (int r = 0; r < 4; ++r) {
            iv4 mv = buf[c % 3][r];
#pragma unroll
            for (int q = 0; q < 4; ++q) {
                float e  = s1r[r] + ((const float*)&s2v)[q];
                float ev = __expf(fmaxf(e, 0.f) + ALPHA * fminf(e, 0.f));
                float contrib = ((mv[q] > 0) ? ev : 1.0f) * vw;   // expf(9e-15)==1.0f exactly
                acc[r][0] += contrib;
                acc[r][1] += contrib * hx[q];
                acc[r][2] += contrib * hy[q];
                acc[r][3] += contrib * hz[q];
            }
        }
    }

#pragma unroll
    for (int off = 32; off > 0; off >>= 1)
#pragma unroll
        for (int r = 0; r < 4; ++r) {
            acc[r][0] += __shfl_xor(acc[r][0], off, 64);
            acc[r][1] += __shfl_xor(acc[r][1], off, 64);
            acc[r][2] += __shfl_xor(acc[r][2], off, 64);
            acc[r][3] += __shfl_xor(acc[r][3], off, 64);
        }

    if (lane == 0) {
#pragma unroll
        for (int r = 0; r < 4; ++r) {
            float inv = 1.f / acc[r][0];
            float p0 = acc[r][1] * inv, p1 = acc[r][2] * inv, p2 = acc[r][3] * inv;
            p0 = (p0 > 0.f) ? p0 : expm1f(p0);   // ELU
            p1 = (p1 > 0.f) ? p1 : expm1f(p1);
            p2 = (p2 > 0.f) ? p2 : expm1f(p2);
            if (mode == 2) {
                _Float16* x16 = (_Float16*)((char*)wsf + WS_X_OFF);
                int i = i_base + 4 * w + r;
                x16[(size_t)(3 * i + 0) * 8 + b] = (_Float16)p0;
                x16[(size_t)(3 * i + 1) * 8 + b] = (_Float16)p1;
                x16[(size_t)(3 * i + 2) * 8 + b] = (_Float16)p2;
            } else {
                int cc = 3 * (4 * w + r);
                xblk[cc + 0] = p0; xblk[cc + 1] = p1; xblk[cc + 2] = p2;
            }
        }
    }

    if (mode != 2) {
        __syncthreads();
        int k = (t + R0) & 255;
        const float* wr = fc1_w + (size_t)k * (N_ENT * 3) + 3 * i_base;
        float d = 0.f;
#pragma unroll
        for (int c4 = 0; c4 < 12; ++c4) {
            float4 wv = *(const float4*)(wr + 4 * c4);
            d += xblk[4 * c4 + 0] * wv.x + xblk[4 * c4 + 1] * wv.y
               + xblk[4 * c4 + 2] * wv.z + xblk[4 * c4 + 3] * wv.w;
        }
        atomicAdd(&out[b * HIDDEN + k], d);
    }
}

// out[b,k] = fc1_b[k] + sum_m x16[m][b] * fc1_w[k][m]; 256 blocks (one per k).
__global__ __launch_bounds__(256) void k_fc(const _Float16* __restrict__ x16,
                                            const float* __restrict__ fc1_w,
                                            const float* __restrict__ fc1_b,
                                            float* __restrict__ out) {
    __shared__ float red[4][8];
    int t = threadIdx.x, lane = t & 63, w = t >> 6;
    int k = blockIdx.x;
    const float* __restrict__ wr = fc1_w + (size_t)k * (N_ENT * 3);
    float acc[BATCH];
#pragma unroll
    for (int b = 0; b < BATCH; ++b) acc[b] = 0.f;
#pragma unroll
    for (int it = 0; it < 6; ++it) {
        int m0 = 4 * t + 1024 * it;
        if (m0 + 3 < N_ENT * 3) {
            float4 wv4 = *(const float4*)(wr + m0);
#pragma unroll
            for (int q = 0; q < 4; ++q) {
                half4 xa = *(const half4*)(x16 + (size_t)(m0 + q) * 8);
                half4 xb = *(const half4*)(x16 + (size_t)(m0 + q) * 8 + 4);
                float wv = ((const float*)&wv4)[q];
                acc[0] += wv * (float)xa[0]; acc[1] += wv * (float)xa[1];
                acc[2] += wv * (float)xa[2]; acc[3] += wv * (float)xa[3];
                acc[4] += wv * (float)xb[0]; acc[5] += wv * (float)xb[1];
                acc[6] += wv * (float)xb[2]; acc[7] += wv * (float)xb[3];
            }
        }
    }
#pragma unroll
    for (int off = 32; off > 0; off >>= 1)
#pragma unroll
        for (int b = 0; b < BATCH; ++b) acc[b] += __shfl_xor(acc[b], off, 64);
    if (lane == 0)
#pragma unroll
        for (int b = 0; b < BATCH; ++b) red[w][b] = acc[b];
    __syncthreads();
    if (t < 8)
        out[t * HIDDEN + k] = red[0][t] + red[1][t] + red[2][t] + red[3][t] + fc1_b[k];
}

extern "C" void kernel_launch(void* const* d_in, const int* in_sizes, int n_in,
                              void* d_out, int out_size, void* d_ws, size_t ws_size,
                              hipStream_t stream) {
    const float* emb   = (const float*)d_in[0];
    const float* W     = (const float*)d_in[1];
    const float* a     = (const float*)d_in[2];
    const float* fc1_w = (const float*)d_in[3];
    const float* fc1_b = (const float*)d_in[4];
    const int*   adj   = (const int*)d_in[5];
    float* out = (float*)d_out;
    float* ws  = (float*)d_ws;
    (void)in_sizes; (void)n_in; (void)out_size;

    int tier = (ws_size >= (size_t)WS_TIER2_BYTES) ? 2
             : (ws_size >= (size_t)WS_TABLE_BYTES) ? 1 : 0;

    if (tier < 2)  k_init<<<8, 256, 0, stream>>>(fc1_b, out);
    if (tier >= 1) k_prep<<<8, 256, 0, stream>>>(emb, W, a, ws);
    k_main<<<1000, 256, 0, stream>>>(emb, W, a, fc1_w, adj, ws, tier, out);
    if (tier == 2)
        k_fc<<<HIDDEN, 256, 0, stream>>>((const _Float16*)((char*)d_ws + WS_X_OFF),
                                         fc1_w, fc1_b, out);
}

// Round 13
// 200.069 us; speedup vs baseline: 1.1770x; 1.0123x over previous
//
#include <hip/hip_runtime.h>
#include <cstddef>

#define N_ENT   2000
#define GAT_EMB 64
#define HIDDEN  256
#define BATCH   8
#define ALPHA   0.2f

typedef _Float16 half4 __attribute__((ext_vector_type(4)));
typedef int iv4 __attribute__((ext_vector_type(4)));
typedef float fv4 __attribute__((ext_vector_type(4)));

// Non-temporal 16B loads: NT bit -> no/evict-first allocation, avoiding
// dirty-victim writeback churn from the harness's 512 MB poison fill + 128 MB
// adj restore that precede every timed launch (r12: -10.7 us measured).
__device__ __forceinline__ iv4 nt_load4i(const int* p) {
    return __builtin_nontemporal_load((const iv4*)p);
}
__device__ __forceinline__ fv4 nt_load4f(const float* p) {
    return __builtin_nontemporal_load((const fv4*)p);
}

// ws byte layout:
//   [0,      8192)   s2f  float[2048]      (pad zeroed by k_prep)
//   [8192,  12288)   hx   _Float16[2048]   (pad zeroed)
//   [12288, 16384)   hy   _Float16[2048]
//   [16384, 20480)   hz   _Float16[2048]
//   [20480, 28672)   s1f  float[2048]
//   [28672, 124672)  x16  _Float16[6000][8]
#define WS_HX_OFF      8192
#define WS_HY_OFF      12288
#define WS_HZ_OFF      16384
#define WS_S1_OFF      20480
#define WS_X_OFF       28672
#define WS_TABLE_BYTES 28672
#define WS_TIER2_BYTES 124672

__global__ __launch_bounds__(256) void k_init(const float* __restrict__ fc1_b,
                                              float* __restrict__ out) {
    int idx = blockIdx.x * 256 + threadIdx.x;
    out[idx] = fc1_b[idx & (HIDDEN - 1)];
}

// Table build; 2048 threads cover the pad (zeroed).
__global__ __launch_bounds__(256) void k_prep(const float* __restrict__ emb,
                                              const float* __restrict__ W,
                                              const float* __restrict__ a,
                                              float* __restrict__ ws) {
    __shared__ float sW[GAT_EMB * 3];
    __shared__ float sa[6];
    int t = threadIdx.x;
    if (t < GAT_EMB * 3) sW[t] = W[t];
    if (t < 6)           sa[t] = a[t];
    __syncthreads();
    int i = blockIdx.x * 256 + t;
    if (i >= 2048) return;
    if (i >= N_ENT) {
        ws[i] = 0.f;
        ((_Float16*)((char*)ws + WS_HX_OFF))[i] = (_Float16)0;
        ((_Float16*)((char*)ws + WS_HY_OFF))[i] = (_Float16)0;
        ((_Float16*)((char*)ws + WS_HZ_OFF))[i] = (_Float16)0;
        ws[WS_S1_OFF / 4 + i] = 0.f;
        return;
    }
    const float4* er = (const float4*)(emb + (size_t)i * GAT_EMB);
    float h0 = 0.f, h1 = 0.f, h2 = 0.f;
#pragma unroll
    for (int k4 = 0; k4 < GAT_EMB / 4; ++k4) {
        float4 e4 = er[k4];
        int k = 4 * k4;
        h0 += e4.x * sW[(k + 0) * 3 + 0]; h1 += e4.x * sW[(k + 0) * 3 + 1]; h2 += e4.x * sW[(k + 0) * 3 + 2];
        h0 += e4.y * sW[(k + 1) * 3 + 0]; h1 += e4.y * sW[(k + 1) * 3 + 1]; h2 += e4.y * sW[(k + 1) * 3 + 2];
        h0 += e4.z * sW[(k + 2) * 3 + 0]; h1 += e4.z * sW[(k + 2) * 3 + 1]; h2 += e4.z * sW[(k + 2) * 3 + 2];
        h0 += e4.w * sW[(k + 3) * 3 + 0]; h1 += e4.w * sW[(k + 3) * 3 + 1]; h2 += e4.w * sW[(k + 3) * 3 + 2];
    }
    ws[i] = h0 * sa[3] + h1 * sa[4] + h2 * sa[5];                       // s2
    ((_Float16*)((char*)ws + WS_HX_OFF))[i] = (_Float16)h0;
    ((_Float16*)((char*)ws + WS_HY_OFF))[i] = (_Float16)h1;
    ((_Float16*)((char*)ws + WS_HZ_OFF))[i] = (_Float16)h2;
    ws[WS_S1_OFF / 4 + i] = h0 * sa[0] + h1 * sa[1] + h2 * sa[2];       // s1
}

// r12 + occupancy: 2000 blocks x 8 contiguous rows (one batch b each);
// wave w: rows i_base+2w..+1 (2 NT streams 8 KB apart), 2-chunk-ahead
// 3-buffer register prefetch. LDS 20.5 KB -> 7 blocks/CU; 2000 blocks fill it.
__global__ __launch_bounds__(256, 4) void k_main(const float* __restrict__ emb,
                                                 const float* __restrict__ W,
                                                 const float* __restrict__ a,
                                                 const float* __restrict__ fc1_w,
                                                 const int*   __restrict__ adj,
                                                 float* __restrict__ wsf,
                                                 int mode,
                                                 float* __restrict__ out) {
    __shared__ __align__(16) unsigned char smem[20480];
    float*    s2s = (float*)smem;
    _Float16* hxs = (_Float16*)(smem + 8192);
    _Float16* hys = (_Float16*)(smem + 12288);
    _Float16* hzs = (_Float16*)(smem + 16384);
    __shared__ float sW[GAT_EMB * 3];
    __shared__ float sa[6];
    __shared__ float s1sh[8];
    __shared__ float xblk[24];

    int t = threadIdx.x;
    int R0 = blockIdx.x * 8;         // global row (b*N_ENT + i); 8 | 2000 -> no straddle
    int b  = R0 / N_ENT;
    int i_base = R0 - b * N_ENT;

    if (mode != 0) {
        const uint4* src = (const uint4*)wsf;
        uint4* dst = (uint4*)smem;
#pragma unroll
        for (int rep = 0; rep < 5; ++rep) dst[rep * 256 + t] = src[rep * 256 + t];  // 20480 B
        if (t < 8) s1sh[t] = wsf[WS_S1_OFF / 4 + i_base + t];
    } else {
        if (t < GAT_EMB * 3) sW[t] = W[t];
        if (t < 6)           sa[t] = a[t];
        __syncthreads();
        for (int j = t; j < N_ENT; j += 256) {
            const float4* er = (const float4*)(emb + (size_t)j * GAT_EMB);
            float h0 = 0.f, h1 = 0.f, h2 = 0.f;
#pragma unroll
            for (int k4 = 0; k4 < GAT_EMB / 4; ++k4) {
                float4 e4 = er[k4];
                int k = 4 * k4;
                h0 += e4.x * sW[(k + 0) * 3 + 0]; h1 += e4.x * sW[(k + 0) * 3 + 1]; h2 += e4.x * sW[(k + 0) * 3 + 2];
                h0 += e4.y * sW[(k + 1) * 3 + 0]; h1 += e4.y * sW[(k + 1) * 3 + 1]; h2 += e4.y * sW[(k + 1) * 3 + 2];
                h0 += e4.z * sW[(k + 2) * 3 + 0]; h1 += e4.z * sW[(k + 2) * 3 + 1]; h2 += e4.z * sW[(k + 2) * 3 + 2];
                h0 += e4.w * sW[(k + 3) * 3 + 0]; h1 += e4.w * sW[(k + 3) * 3 + 1]; h2 += e4.w * sW[(k + 3) * 3 + 2];
            }
            s2s[j] = h0 * sa[3] + h1 * sa[4] + h2 * sa[5];
            hxs[j] = (_Float16)h0; hys[j] = (_Float16)h1; hzs[j] = (_Float16)h2;
            if (j >= i_base && j < i_base + 8)
                s1sh[j - i_base] = h0 * sa[0] + h1 * sa[1] + h2 * sa[2];
        }
        if (t < 2048 - N_ENT) {
            int j = N_ENT + t;
            s2s[j] = 0.f; hxs[j] = (_Float16)0; hys[j] = (_Float16)0; hzs[j] = (_Float16)0;
        }
    }
    __syncthreads();

    // ---- Phase 2: 2 rows/wave, 8 chunks, 2-chunk-ahead NT prefetch ----
    int lane = t & 63;
    int w    = t >> 6;
    float s1r[2];
    const int* __restrict__ rowp[2];
#pragma unroll
    for (int r = 0; r < 2; ++r) {
        s1r[r] = s1sh[2 * w + r];
        rowp[r] = adj + ((size_t)b * N_ENT + (i_base + 2 * w + r)) * N_ENT;
    }

    float acc[2][4];
#pragma unroll
    for (int r = 0; r < 2; ++r) { acc[r][0] = 0.f; acc[r][1] = 0.f; acc[r][2] = 0.f; acc[r][3] = 0.f; }

    int l4 = lane << 2;
    iv4 buf[3][2];
#pragma unroll
    for (int r = 0; r < 2; ++r) buf[0][r] = nt_load4i(rowp[r] + l4);
#pragma unroll
    for (int r = 0; r < 2; ++r) buf[1][r] = nt_load4i(rowp[r] + 256 + l4);

#pragma unroll
    for (int c = 0; c < 8; ++c) {
        if (c + 2 < 8) {
            int j2 = (c + 2) * 256 + l4;
            int jc2 = (j2 < N_ENT) ? j2 : 0;
#pragma unroll
            for (int r = 0; r < 2; ++r)
                buf[(c + 2) % 3][r] = nt_load4i(rowp[r] + jc2);
        }
        int j0 = c * 256 + l4;                 // <= 2044; LDS pad zeroed
        bool valid = (j0 < N_ENT);
        float vw = valid ? 1.0f : 0.0f;
        float4 s2v = *(const float4*)&s2s[j0];
        half4  hxv = *(const half4*)&hxs[j0];
        half4  hyv = *(const half4*)&hys[j0];
        half4  hzv = *(const half4*)&hzs[j0];
        float hx[4], hy[4], hz[4];
#pragma unroll
        for (int q = 0; q < 4; ++q) { hx[q] = (float)hxv[q]; hy[q] = (float)hyv[q]; hz[q] = (float)hzv[q]; }
#pragma unroll
        for (int r = 0; r < 2; ++r) {
            iv4 mv = buf[c % 3][r];
#pragma unroll
            for (int q = 0; q < 4; ++q) {
                float e  = s1r[r] + ((const float*)&s2v)[q];
                float ev = __expf(fmaxf(e, 0.f) + ALPHA * fminf(e, 0.f));
                float contrib = ((mv[q] > 0) ? ev : 1.0f) * vw;   // expf(9e-15)==1.0f exactly
                acc[r][0] += contrib;
                acc[r][1] += contrib * hx[q];
                acc[r][2] += contrib * hy[q];
                acc[r][3] += contrib * hz[q];
            }
        }
    }

#pragma unroll
    for (int off = 32; off > 0; off >>= 1)
#pragma unroll
        for (int r = 0; r < 2; ++r) {
            acc[r][0] += __shfl_xor(acc[r][0], off, 64);
            acc[r][1] += __shfl_xor(acc[r][1], off, 64);
            acc[r][2] += __shfl_xor(acc[r][2], off, 64);
            acc[r][3] += __shfl_xor(acc[r][3], off, 64);
        }

    if (lane == 0) {
#pragma unroll
        for (int r = 0; r < 2; ++r) {
            float inv = 1.f / acc[r][0];
            float p0 = acc[r][1] * inv, p1 = acc[r][2] * inv, p2 = acc[r][3] * inv;
            p0 = (p0 > 0.f) ? p0 : expm1f(p0);   // ELU
            p1 = (p1 > 0.f) ? p1 : expm1f(p1);
            p2 = (p2 > 0.f) ? p2 : expm1f(p2);
            if (mode == 2) {
                _Float16* x16 = (_Float16*)((char*)wsf + WS_X_OFF);
                int i = i_base + 2 * w + r;
                x16[(size_t)(3 * i + 0) * 8 + b] = (_Float16)p0;
                x16[(size_t)(3 * i + 1) * 8 + b] = (_Float16)p1;
                x16[(size_t)(3 * i + 2) * 8 + b] = (_Float16)p2;
            } else {
                int cc = 3 * (2 * w + r);
                xblk[cc + 0] = p0; xblk[cc + 1] = p1; xblk[cc + 2] = p2;
            }
        }
    }

    if (mode != 2) {   // fallback: atomic FC for this block's 24 columns, one batch b
        __syncthreads();
        int k = (t + R0) & 255;
        const float* wr = fc1_w + (size_t)k * (N_ENT * 3) + 3 * i_base;  // 24 floats, 8B-aligned
        float d = 0.f;
#pragma unroll
        for (int c2 = 0; c2 < 12; ++c2) {
            float2 wv = *(const float2*)(wr + 2 * c2);
            d += xblk[2 * c2 + 0] * wv.x + xblk[2 * c2 + 1] * wv.y;
        }
        atomicAdd(&out[b * HIDDEN + k], d);
    }
}

// out[b,k] = fc1_b[k] + sum_m x16[m][b] * fc1_w[k][m]; 256 blocks (one per k).
// fc1_w via NT loads (6 MB through poison-dirtied caches).
__global__ __launch_bounds__(256) void k_fc(const _Float16* __restrict__ x16,
                                            const float* __restrict__ fc1_w,
                                            const float* __restrict__ fc1_b,
                                            float* __restrict__ out) {
    __shared__ float red[4][8];
    int t = threadIdx.x, lane = t & 63, w = t >> 6;
    int k = blockIdx.x;
    const float* __restrict__ wr = fc1_w + (size_t)k * (N_ENT * 3);
    float acc[BATCH];
#pragma unroll
    for (int b = 0; b < BATCH; ++b) acc[b] = 0.f;
#pragma unroll
    for (int it = 0; it < 6; ++it) {
        int m0 = 4 * t + 1024 * it;
        if (m0 + 3 < N_ENT * 3) {
            fv4 wv4 = nt_load4f(wr + m0);
#pragma unroll
            for (int q = 0; q < 4; ++q) {
                half4 xa = *(const half4*)(x16 + (size_t)(m0 + q) * 8);
                half4 xb = *(const half4*)(x16 + (size_t)(m0 + q) * 8 + 4);
                float wv = wv4[q];
                acc[0] += wv * (float)xa[0]; acc[1] += wv * (float)xa[1];
                acc[2] += wv * (float)xa[2]; acc[3] += wv * (float)xa[3];
                acc[4] += wv * (float)xb[0]; acc[5] += wv * (float)xb[1];
                acc[6] += wv * (float)xb[2]; acc[7] += wv * (float)xb[3];
            }
        }
    }
#pragma unroll
    for (int off = 32; off > 0; off >>= 1)
#pragma unroll
        for (int b = 0; b < BATCH; ++b) acc[b] += __shfl_xor(acc[b], off, 64);
    if (lane == 0)
#pragma unroll
        for (int b = 0; b < BATCH; ++b) red[w][b] = acc[b];
    __syncthreads();
    if (t < 8)
        out[t * HIDDEN + k] = red[0][t] + red[1][t] + red[2][t] + red[3][t] + fc1_b[k];
}

extern "C" void kernel_launch(void* const* d_in, const int* in_sizes, int n_in,
                              void* d_out, int out_size, void* d_ws, size_t ws_size,
                              hipStream_t stream) {
    const float* emb   = (const float*)d_in[0];
    const float* W     = (const float*)d_in[1];
    const float* a     = (const float*)d_in[2];
    const float* fc1_w = (const float*)d_in[3];
    const float* fc1_b = (const float*)d_in[4];
    const int*   adj   = (const int*)d_in[5];
    float* out = (float*)d_out;
    float* ws  = (float*)d_ws;
    (void)in_sizes; (void)n_in; (void)out_size;

    int tier = (ws_size >= (size_t)WS_TIER2_BYTES) ? 2
             : (ws_size >= (size_t)WS_TABLE_BYTES) ? 1 : 0;

    if (tier < 2)  k_init<<<8, 256, 0, stream>>>(fc1_b, out);
    if (tier >= 1) k_prep<<<8, 256, 0, stream>>>(emb, W, a, ws);
    k_main<<<N_ENT, 256, 0, stream>>>(emb, W, a, fc1_w, adj, ws, tier, out);
    if (tier == 2)
        k_fc<<<HIDDEN, 256, 0, stream>>>((const _Float16*)((char*)d_ws + WS_X_OFF),
                                         fc1_w, fc1_b, out);
}